// Round 1
// baseline (1284.444 us; speedup 1.0000x reference)
//
#include <hip/hip_runtime.h>
#include <hip/hip_bf16.h>
#include <cstdint>
#include <cstddef>

// Problem dims
#define Bn 64
#define Tn 2048
#define Mn 1024   // MEMORY_SIZE (GEMM K)
#define An 512    // ATTN_SIZE
#define Qn 1024   // QUERY_SIZE

typedef __attribute__((ext_vector_type(8))) short short8;
typedef __attribute__((ext_vector_type(4))) float f32x4;
typedef __attribute__((ext_vector_type(4))) unsigned short us4;

static __device__ __forceinline__ unsigned short f2bf(float f) {
  uint32_t u = __float_as_uint(f);
  u += 0x7fff + ((u >> 16) & 1);   // RNE
  return (unsigned short)(u >> 16);
}
static __device__ __forceinline__ float bf2f(unsigned short s) {
  return __uint_as_float(((uint32_t)s) << 16);
}

// ---------------- prep kernels ----------------
// zero context-accumulator region of d_out and Z accumulator (d_ws/d_out are 0xAA-poisoned)
__global__ void zero_kernel(float* __restrict__ ctx, float* __restrict__ Zacc) {
  int i = blockIdx.x * 256 + threadIdx.x;
  if (i < Bn * Mn) ctx[i] = 0.0f;
  else if (i < Bn * Mn + Bn) Zacc[i - Bn * Mn] = 0.0f;
}

__global__ void cvt_wm_kernel(const float* __restrict__ Wm, unsigned short* __restrict__ out) {
  int i = blockIdx.x * 256 + threadIdx.x;
  if (i < An * Mn) out[i] = f2bf(Wm[i]);
}

// w_query[b][a] = sum_m query[b][m] * W_query[a][m]  (fp32, exact path — tiny)
__global__ void wq_kernel(const float* __restrict__ query, const float* __restrict__ Wq,
                          float* __restrict__ wqout) {
  __shared__ __align__(16) float qs[Qn];
  const int b = blockIdx.x;
  const int tid = threadIdx.x;  // 512 threads, one output column each
  qs[tid] = query[b * Qn + tid];
  qs[tid + 512] = query[b * Qn + tid + 512];
  __syncthreads();
  const f32x4* w = (const f32x4*)(Wq + (size_t)tid * Qn);
  const f32x4* q4 = (const f32x4*)qs;
  float acc = 0.f;
#pragma unroll 8
  for (int m = 0; m < Qn / 4; ++m) {
    f32x4 wv = w[m];
    f32x4 qv = q4[m];
    acc += wv.x * qv.x + wv.y * qv.y + wv.z * qv.z + wv.w * qv.w;
  }
  wqout[b * An + tid] = acc;
}

// ---------------- fused main kernel ----------------
// One block = one (b, 64-row t-tile). 512 threads = 8 waves in a 2x4 (row x col) grid.
// Phase 1: GEMM  wm[64 x 512] = mem_tile[64 x 1024] * Wm^T   (bf16 MFMA 16x16x32)
//          memory tile staged fp32->bf16 into LDS in BK=32 chunks, pipelined 1 ahead.
// Phase 2: scores s_t = sum_a v_a * tanh(wq[b,a] + wm[t,a]);  e_t = exp(s_t) -> d_out (unnormalized)
// Phase 3: context partial sum_t e_t * mem[t,m] from the SAME LDS tile -> atomicAdd to d_out ctx region
#define RT 64
#define BK 32
#define NKC (Mn / BK)
#define LSTRIDE (Mn + 8)   // ushort stride per LDS row (pad to break bank-conflict power-of-2)

__launch_bounds__(512, 2)
__global__ void fused_kernel(const float* __restrict__ mem,
                             const float* __restrict__ wq,
                             const unsigned short* __restrict__ Wm,
                             const float* __restrict__ Wv,
                             float* __restrict__ out,
                             float* __restrict__ Zacc) {
  __shared__ __align__(16) unsigned short tile[RT * LSTRIDE];  // 129 KB
  __shared__ float s_score[RT];
  __shared__ float s_e[RT];

  const int tid = threadIdx.x;
  const int b = blockIdx.x & (Bn - 1);
  const int tt = blockIdx.x >> 6;
  const int t0 = tt * RT;

  const int lane = tid & 63;
  const int wave = tid >> 6;
  const int wr = wave >> 2;   // 0..1 : 32-row half
  const int wc = wave & 3;    // 0..3 : 128-col chunk
  const int l15 = lane & 15;
  const int quad = lane >> 4; // 0..3

  if (tid < RT) s_score[tid] = 0.0f;

  // staging: each thread loads 4 fp32 per chunk (64 rows x 32 k = 2048 elems / 512 thr)
  const int srow = tid >> 3;
  const int skp = (tid & 7) * 4;
  const float* src = mem + ((size_t)(b * Tn + t0 + srow)) * Mn + skp;
  unsigned short* dst = &tile[srow * LSTRIDE + skp];

  {  // stage chunk 0
    f32x4 v = *(const f32x4*)src;
    us4 o; o.x = f2bf(v.x); o.y = f2bf(v.y); o.z = f2bf(v.z); o.w = f2bf(v.w);
    *(us4*)dst = o;
  }
  __syncthreads();

  f32x4 acc[2][8] = {};

  // MFMA operand bases: A (mem tile, LDS), B (Wm, global/L2): lane&15 -> row/col, (lane>>4)*8 -> k
  const unsigned short* wp = Wm + (size_t)(wc * 128 + l15) * Mn + quad * 8;
  const unsigned short* ap = &tile[(wr * 32 + l15) * LSTRIDE + quad * 8];

  for (int kc = 0; kc < NKC; ++kc) {
    f32x4 nxt;
    if (kc + 1 < NKC) nxt = *(const f32x4*)(src + (kc + 1) * BK);

    short8 bfrag[8];
#pragma unroll
    for (int c = 0; c < 8; ++c)
      bfrag[c] = *(const short8*)(wp + (size_t)c * (16 * Mn) + kc * BK);

    short8 afrag[2];
#pragma unroll
    for (int r = 0; r < 2; ++r)
      afrag[r] = *(const short8*)(ap + r * (16 * LSTRIDE) + kc * BK);

#pragma unroll
    for (int r = 0; r < 2; ++r)
#pragma unroll
      for (int c = 0; c < 8; ++c)
        acc[r][c] = __builtin_amdgcn_mfma_f32_16x16x32_bf16(afrag[r], bfrag[c], acc[r][c], 0, 0, 0);

    if (kc + 1 < NKC) {  // write next chunk to its (distinct) LDS slice
      us4 o; o.x = f2bf(nxt.x); o.y = f2bf(nxt.y); o.z = f2bf(nxt.z); o.w = f2bf(nxt.w);
      *(us4*)(dst + (kc + 1) * BK) = o;
    }
    __syncthreads();
  }

  // ---- scores: s_t = sum_a v_a * tanh(wq + wm) ----
  // C/D layout (m89-verified): col = lane&15, row = quad*4 + reg
  const float* wqb = wq + b * An;
  {
    float rs[2][4];
#pragma unroll
    for (int r = 0; r < 2; ++r)
#pragma unroll
      for (int g = 0; g < 4; ++g) rs[r][g] = 0.f;

#pragma unroll
    for (int c = 0; c < 8; ++c) {
      const int a = wc * 128 + c * 16 + l15;
      const float wqa = wqb[a];
      const float va = Wv[a];
#pragma unroll
      for (int r = 0; r < 2; ++r) {
#pragma unroll
        for (int g = 0; g < 4; ++g) {
          float x = wqa + acc[r][c][g];
          float ez = __expf(2.0f * x);                         // tanh via exp
          float th = 1.0f - 2.0f * __builtin_amdgcn_rcpf(ez + 1.0f);
          rs[r][g] += va * th;
        }
      }
    }
    // butterfly over lane bits 0..3 sums the 16 columns held by a quad-row group
#pragma unroll
    for (int r = 0; r < 2; ++r) {
#pragma unroll
      for (int g = 0; g < 4; ++g) {
        float v = rs[r][g];
        v += __shfl_xor(v, 1);
        v += __shfl_xor(v, 2);
        v += __shfl_xor(v, 4);
        v += __shfl_xor(v, 8);
        if (l15 == 0) {
          int row = wr * 32 + r * 16 + quad * 4 + g;
          atomicAdd(&s_score[row], v);   // combine the 4 col-chunk waves
        }
      }
    }
  }
  __syncthreads();

  // ---- e_t, Z partial; write unnormalized alpha ----
  if (tid < RT) {
    float e = __expf(s_score[tid]);   // |s| <= 22.6 -> no overflow, no max-sub needed
    s_e[tid] = e;
    out[(size_t)b * Tn + t0 + tid] = e;
    float z = e;
    z += __shfl_xor(z, 1);
    z += __shfl_xor(z, 2);
    z += __shfl_xor(z, 4);
    z += __shfl_xor(z, 8);
    z += __shfl_xor(z, 16);
    z += __shfl_xor(z, 32);
    if (lane == 0) atomicAdd(&Zacc[b], z);
  }
  __syncthreads();

  // ---- context partial from the resident LDS tile ----
  {
    float c0 = 0.f, c1 = 0.f;
    const uint32_t* trow = (const uint32_t*)tile;  // dword view; LSTRIDE/2 dwords per row
#pragma unroll 4
    for (int r = 0; r < RT; ++r) {
      uint32_t wv = trow[r * (LSTRIDE / 2) + tid];
      float e = s_e[r];
      c0 += e * bf2f((unsigned short)(wv & 0xffffu));
      c1 += e * bf2f((unsigned short)(wv >> 16));
    }
    float* ctx = out + Bn * Tn + (size_t)b * Mn;
    atomicAdd(&ctx[2 * tid], c0);
    atomicAdd(&ctx[2 * tid + 1], c1);
  }
}

// ---------------- finalize: divide by Z ----------------
__global__ void finalize_kernel(float* __restrict__ out, const float* __restrict__ Zacc) {
  int i = blockIdx.x * 256 + threadIdx.x;
  if (i < Bn * Tn) {
    int b = i >> 11;           // / Tn
    out[i] /= Zacc[b];
  } else if (i < Bn * Tn + Bn * Mn) {
    int j = i - Bn * Tn;
    int b = j >> 10;           // / Mn
    out[i] /= Zacc[b];
  }
}

extern "C" void kernel_launch(void* const* d_in, const int* in_sizes, int n_in,
                              void* d_out, int out_size, void* d_ws, size_t ws_size,
                              hipStream_t stream) {
  const float* query    = (const float*)d_in[0];  // [64,1024]
  const float* memory   = (const float*)d_in[1];  // [64,2048,1024]
  const float* W_query  = (const float*)d_in[2];  // [512,1024]
  const float* W_memory = (const float*)d_in[3];  // [512,1024]
  const float* W_v      = (const float*)d_in[4];  // [1,512]
  float* out = (float*)d_out;                     // alpha[64,2048] ++ context[64,1024]

  // workspace layout: wq (128 KB) | Wm bf16 (1 MB) | Zacc (256 B)  => ~1.13 MB
  float* wq = (float*)d_ws;
  unsigned short* Wmb = (unsigned short*)((char*)d_ws + (size_t)Bn * An * 4);
  float* Zacc = (float*)((char*)d_ws + (size_t)Bn * An * 4 + (size_t)An * Mn * 2);

  zero_kernel<<<(Bn * Mn + Bn + 255) / 256, 256, 0, stream>>>(out + Bn * Tn, Zacc);
  cvt_wm_kernel<<<(An * Mn + 255) / 256, 256, 0, stream>>>(W_memory, Wmb);
  wq_kernel<<<Bn, 512, 0, stream>>>(query, W_query, wq);
  fused_kernel<<<Bn * (Tn / RT), 512, 0, stream>>>(memory, wq, Wmb, W_v, out, Zacc);
  finalize_kernel<<<(Bn * Tn + Bn * Mn + 255) / 256, 256, 0, stream>>>(out, Zacc);
}

// Round 2
// 898.410 us; speedup vs baseline: 1.4297x; 1.4297x over previous
//
#include <hip/hip_runtime.h>
#include <hip/hip_bf16.h>
#include <cstdint>
#include <cstddef>

// Problem dims
#define Bn 64
#define Tn 2048
#define Mn 1024   // MEMORY_SIZE (GEMM K)
#define An 512    // ATTN_SIZE
#define Qn 1024   // QUERY_SIZE

#define RT 64     // t-rows per block
#define BK 32     // k-chunk
#define NKC (Mn / BK)

typedef __attribute__((ext_vector_type(8))) short short8;
typedef __attribute__((ext_vector_type(4))) float f32x4;
typedef __attribute__((ext_vector_type(2))) float f32x2;
typedef __attribute__((ext_vector_type(4))) unsigned short us4;

static __device__ __forceinline__ unsigned short f2bf(float f) {
  uint32_t u = __float_as_uint(f);
  u += 0x7fff + ((u >> 16) & 1);   // RNE
  return (unsigned short)(u >> 16);
}

static __device__ __forceinline__ void gl_lds16(const void* g, void* l) {
  __builtin_amdgcn_global_load_lds(
      (const __attribute__((address_space(1))) unsigned int*)g,
      (__attribute__((address_space(3))) unsigned int*)l, 16, 0, 0);
}

// ---------------- prep kernels ----------------
__global__ void zero_kernel(float* __restrict__ ctx, float* __restrict__ Zacc) {
  int i = blockIdx.x * 256 + threadIdx.x;
  if (i < Bn * Mn) ctx[i] = 0.0f;
  else if (i < Bn * Mn + Bn) Zacc[i - Bn * Mn] = 0.0f;
}

__global__ void cvt_wm_kernel(const float* __restrict__ Wm, unsigned short* __restrict__ out) {
  int i = blockIdx.x * 256 + threadIdx.x;
  if (i < An * Mn) out[i] = f2bf(Wm[i]);
}

// w_query[b][a] = sum_m query[b][m] * W_query[a][m]  (fp32 exact, tiny)
__global__ void wq_kernel(const float* __restrict__ query, const float* __restrict__ Wq,
                          float* __restrict__ wqout) {
  __shared__ __align__(16) float qs[Qn];
  const int b = blockIdx.x >> 2;
  const int ag = blockIdx.x & 3;
  const int tid = threadIdx.x;  // 128
  for (int i = tid; i < Qn; i += 128) qs[i] = query[b * Qn + i];
  __syncthreads();
  const int a = ag * 128 + tid;
  const f32x4* w = (const f32x4*)(Wq + (size_t)a * Qn);
  const f32x4* q4 = (const f32x4*)qs;
  float acc = 0.f;
#pragma unroll 8
  for (int m = 0; m < Qn / 4; ++m) {
    f32x4 wv = w[m];
    f32x4 qv = q4[m];
    acc += wv.x * qv.x + wv.y * qv.y + wv.z * qv.z + wv.w * qv.w;
  }
  wqout[b * An + a] = acc;
}

// ---------------- fused main kernel ----------------
// Block = (b, 64-row t-tile), 512 thr = 8 waves. Wave w handles ALL 64 rows x 64-col slice.
// K-loop: A (memory, fp32->bf16 via regs) + B (Wmb bf16 via global_load_lds) double-buffered
// in LDS, one barrier/iter. 16-B units XOR-swizzled: ds_read_b128 frags are 2-way (free).
// Phase 2: scores + exp. Phase 3: context partial from global re-read (L2/L3-hot).
__launch_bounds__(512, 4)  // 2 blocks/CU (LDS 72.6 KB), needs <=128 VGPR
__global__ void fused_kernel(const float* __restrict__ mem,
                             const float* __restrict__ wq,
                             const unsigned short* __restrict__ Wmb,
                             const float* __restrict__ Wv,
                             float* __restrict__ out,
                             float* __restrict__ Zacc) {
  __shared__ __align__(16) unsigned short As[2][RT * BK];   // 2 x 4 KB
  __shared__ __align__(16) unsigned short Bs[2][An * BK];   // 2 x 32 KB
  __shared__ float s_score[RT];
  __shared__ float s_e[RT];

  const int tid = threadIdx.x;
  const int b  = blockIdx.x & (Bn - 1);
  const int tt = blockIdx.x >> 6;
  const int t0 = tt * RT;

  const int lane = tid & 63;
  const int w = tid >> 6;        // wave 0..7 -> col slice w*64
  const int l15 = lane & 15;
  const int quad = lane >> 4;

  if (tid < RT) s_score[tid] = 0.f;

  // A staging: thread -> (row=tid>>3, 4-float k-group h=tid&7)
  const int arow = tid >> 3;
  const int ah = tid & 7;
  const float* asrc = mem + ((size_t)(b * Tn + t0 + arow)) * Mn + ah * 4;
  const int au = ((ah >> 1) + (arow >> 1)) & 3;              // physical 16B unit
  const int aoff = arow * BK + au * 8 + (ah & 1) * 4;        // ushort index

  // B staging: wave w stages slices s=w*4+i (16 a-rows each) via global_load_lds
  const int ba0 = w * 64 + (lane >> 2);   // a for issue 0
  const int bj = lane & 3;                // physical 16B slot within a-row

  // fragment read offsets (ushort idx), swizzle u=(quad+(row>>1))&3
  int aro[4], bro[4];
#pragma unroll
  for (int rt = 0; rt < 4; ++rt) {
    int row = rt * 16 + l15;
    aro[rt] = row * BK + (((quad + (row >> 1)) & 3) * 8);
  }
#pragma unroll
  for (int ct = 0; ct < 4; ++ct) {
    int a = w * 64 + ct * 16 + l15;
    bro[ct] = a * BK + (((quad + (a >> 1)) & 3) * 8);
  }

  // ---- stage chunk 0 ----
  f32x4 av = *(const f32x4*)asrc;
  {
    us4 o; o.x = f2bf(av.x); o.y = f2bf(av.y); o.z = f2bf(av.z); o.w = f2bf(av.w);
    *(us4*)&As[0][aoff] = o;
  }
#pragma unroll
  for (int i = 0; i < 4; ++i) {
    int a = ba0 + i * 16;
    int q = (bj - (a >> 1)) & 3;                 // logical k-octet stored at slot bj
    gl_lds16(Wmb + (size_t)a * Mn + q * 8, &Bs[0][(size_t)(w * 4 + i) * 512]);
  }
  __syncthreads();

  f32x4 acc[4][4] = {};   // [row-tile][col-tile]

  for (int kc = 0; kc < NKC; ++kc) {
    const int p = kc & 1, np = p ^ 1;
    if (kc + 1 < NKC) {
      av = *(const f32x4*)(asrc + (kc + 1) * BK);          // A prefetch (regs)
#pragma unroll
      for (int i = 0; i < 4; ++i) {                        // B prefetch (async -> LDS)
        int a = ba0 + i * 16;
        int q = (bj - (a >> 1)) & 3;
        gl_lds16(Wmb + (size_t)a * Mn + (kc + 1) * BK + q * 8,
                 &Bs[np][(size_t)(w * 4 + i) * 512]);
      }
    }

    short8 af[4], bf[4];
#pragma unroll
    for (int i = 0; i < 4; ++i) af[i] = *(const short8*)&As[p][aro[i]];
#pragma unroll
    for (int i = 0; i < 4; ++i) bf[i] = *(const short8*)&Bs[p][bro[i]];

#pragma unroll
    for (int rt = 0; rt < 4; ++rt)
#pragma unroll
      for (int ct = 0; ct < 4; ++ct)
        acc[rt][ct] = __builtin_amdgcn_mfma_f32_16x16x32_bf16(af[rt], bf[ct], acc[rt][ct], 0, 0, 0);

    if (kc + 1 < NKC) {   // write prefetched A into next buffer
      us4 o; o.x = f2bf(av.x); o.y = f2bf(av.y); o.z = f2bf(av.z); o.w = f2bf(av.w);
      *(us4*)&As[np][aoff] = o;
    }
    __syncthreads();
  }

  // ---- phase 2: scores s_t = sum_a v_a * tanh(wq_a + wm[t][a]) ----
  // C/D layout: col = lane&15 (a), row = quad*4 + reg (t)
  const float* wqb = wq + b * An;
  {
    float rs[4][4];
#pragma unroll
    for (int rt = 0; rt < 4; ++rt)
#pragma unroll
      for (int g = 0; g < 4; ++g) rs[rt][g] = 0.f;

#pragma unroll
    for (int ct = 0; ct < 4; ++ct) {
      const int a = w * 64 + ct * 16 + l15;
      const float wqa = wqb[a];
      const float va = Wv[a];
#pragma unroll
      for (int rt = 0; rt < 4; ++rt) {
#pragma unroll
        for (int g = 0; g < 4; ++g) {
          float x = wqa + acc[rt][ct][g];
          float ez = __expf(2.0f * x);
          float th = 1.0f - 2.0f * __builtin_amdgcn_rcpf(ez + 1.0f);
          rs[rt][g] += va * th;
        }
      }
    }
#pragma unroll
    for (int rt = 0; rt < 4; ++rt) {
#pragma unroll
      for (int g = 0; g < 4; ++g) {
        float v = rs[rt][g];
        v += __shfl_xor(v, 1);
        v += __shfl_xor(v, 2);
        v += __shfl_xor(v, 4);
        v += __shfl_xor(v, 8);
        if (l15 == 0) atomicAdd(&s_score[rt * 16 + quad * 4 + g], v);
      }
    }
  }
  __syncthreads();

  // ---- e_t, Z partial; write unnormalized alpha ----
  if (tid < RT) {
    float e = __expf(s_score[tid]);   // |s| <= 22.6, fp32-safe without max-sub
    s_e[tid] = e;
    out[(size_t)b * Tn + t0 + tid] = e;
    float z = e;
    z += __shfl_xor(z, 1);
    z += __shfl_xor(z, 2);
    z += __shfl_xor(z, 4);
    z += __shfl_xor(z, 8);
    z += __shfl_xor(z, 16);
    z += __shfl_xor(z, 32);
    if (lane == 0) atomicAdd(&Zacc[b], z);
  }
  __syncthreads();

  // ---- phase 3: context partial, re-read memory (fp32, L2/L3-hot) ----
  {
    const float* mrow = mem + ((size_t)(b * Tn + t0)) * Mn + 2 * tid;
    float c0 = 0.f, c1 = 0.f;
#pragma unroll 8
    for (int r = 0; r < RT; ++r) {
      f32x2 v = *(const f32x2*)(mrow + (size_t)r * Mn);
      float e = s_e[r];
      c0 += e * v.x;
      c1 += e * v.y;
    }
    float* ctx = out + Bn * Tn + (size_t)b * Mn + 2 * tid;
    atomicAdd(&ctx[0], c0);
    atomicAdd(&ctx[1], c1);
  }
}

// ---------------- finalize: divide by Z ----------------
__global__ void finalize_kernel(float* __restrict__ out, const float* __restrict__ Zacc) {
  int i = blockIdx.x * 256 + threadIdx.x;
  if (i < Bn * Tn) {
    int b = i >> 11;           // / Tn
    out[i] /= Zacc[b];
  } else if (i < Bn * Tn + Bn * Mn) {
    int j = i - Bn * Tn;
    int b = j >> 10;           // / Mn
    out[i] /= Zacc[b];
  }
}

extern "C" void kernel_launch(void* const* d_in, const int* in_sizes, int n_in,
                              void* d_out, int out_size, void* d_ws, size_t ws_size,
                              hipStream_t stream) {
  const float* query    = (const float*)d_in[0];  // [64,1024]
  const float* memory   = (const float*)d_in[1];  // [64,2048,1024]
  const float* W_query  = (const float*)d_in[2];  // [512,1024]
  const float* W_memory = (const float*)d_in[3];  // [512,1024]
  const float* W_v      = (const float*)d_in[4];  // [1,512]
  float* out = (float*)d_out;                     // alpha[64,2048] ++ context[64,1024]

  // ws: wq (128 KB) | Wm bf16 (1 MB) | Zacc (256 B)
  float* wq = (float*)d_ws;
  unsigned short* Wmb = (unsigned short*)((char*)d_ws + (size_t)Bn * An * 4);
  float* Zacc = (float*)((char*)d_ws + (size_t)Bn * An * 4 + (size_t)An * Mn * 2);

  zero_kernel<<<(Bn * Mn + Bn + 255) / 256, 256, 0, stream>>>(out + Bn * Tn, Zacc);
  cvt_wm_kernel<<<(An * Mn + 255) / 256, 256, 0, stream>>>(W_memory, Wmb);
  wq_kernel<<<Bn * 4, 128, 0, stream>>>(query, W_query, wq);
  fused_kernel<<<Bn * (Tn / RT), 512, 0, stream>>>(memory, wq, Wmb, W_v, out, Zacc);
  finalize_kernel<<<(Bn * Tn + Bn * Mn + 255) / 256, 256, 0, stream>>>(out, Zacc);
}